// Round 1
// baseline (25.800 us; speedup 1.0000x reference)
//
#include <hip/hip_runtime.h>

#define HIDDEN 2048
#define CHOICE_NUM 19

// One block per hidden unit. Zero initial state => w_hh matmul dead, f-gate dead.
// wave 0 -> gate i (row u), wave 1 -> gate g (row 2H+u), wave 2 -> gate o (row 3H+u).
__global__ __launch_bounds__(192) void lstm_layer_kernel(
    const float* __restrict__ w_ih,   // [4H, H] row-major
    const float* __restrict__ b_ih,   // [4H]
    const float* __restrict__ b_hh,   // [4H]
    const float* __restrict__ x_base, // [*, H]
    const int* __restrict__ idx_ptr,  // optional row index (embedding lookup)
    float* __restrict__ h_out)        // [H]
{
    const int unit = blockIdx.x;
    const int wave = threadIdx.x >> 6;   // 0,1,2
    const int lane = threadIdx.x & 63;

    const int gate_off = (wave == 0) ? 0 : (wave == 1 ? 2 * HIDDEN : 3 * HIDDEN);
    const int row = gate_off + unit;

    const float* x = x_base + (idx_ptr ? (size_t)idx_ptr[0] * HIDDEN : 0);
    const float4* wrow = (const float4*)(w_ih + (size_t)row * HIDDEN);
    const float4* xv   = (const float4*)x;

    float sum = 0.f;
    // 2048/4 = 512 float4 per row; 64 lanes -> 8 float4 per lane, coalesced.
    #pragma unroll
    for (int j = 0; j < 8; ++j) {
        int k = lane + j * 64;
        float4 wv = wrow[k];
        float4 xx = xv[k];
        sum += wv.x * xx.x + wv.y * xx.y + wv.z * xx.z + wv.w * xx.w;
    }
    #pragma unroll
    for (int off = 32; off; off >>= 1)
        sum += __shfl_down(sum, off, 64);

    __shared__ float g_lds[3];
    if (lane == 0) g_lds[wave] = sum + b_ih[row] + b_hh[row];
    __syncthreads();
    if (threadIdx.x == 0) {
        float gi = g_lds[0], gg = g_lds[1], go = g_lds[2];
        float si = 1.f / (1.f + expf(-gi));
        float so = 1.f / (1.f + expf(-go));
        float c  = si * tanhf(gg);
        h_out[unit] = so * tanhf(c);
    }
}

__global__ __launch_bounds__(256) void logits_kernel(
    const float* __restrict__ w_choice, // [19, H]
    const float* __restrict__ b_choice, // [19]
    const float* __restrict__ h,        // [H]
    const int* __restrict__ task_ptr,
    float* __restrict__ out)            // [19]
{
    const int r = blockIdx.x;
    const int t = threadIdx.x;
    const float4* wrow = (const float4*)(w_choice + (size_t)r * HIDDEN);
    const float4* xv   = (const float4*)h;

    float sum = 0.f;
    #pragma unroll
    for (int j = 0; j < 2; ++j) {
        int k = t + j * 256;
        float4 wv = wrow[k];
        float4 xx = xv[k];
        sum += wv.x * xx.x + wv.y * xx.y + wv.z * xx.z + wv.w * xx.w;
    }
    #pragma unroll
    for (int off = 32; off; off >>= 1)
        sum += __shfl_down(sum, off, 64);

    __shared__ float partial[4];
    if ((t & 63) == 0) partial[t >> 6] = sum;
    __syncthreads();
    if (t == 0) {
        float v = partial[0] + partial[1] + partial[2] + partial[3] + b_choice[r];
        int task = task_ptr[0];
        out[r] = (r < 1 + task) ? v : -1e9f;
    }
}

extern "C" void kernel_launch(void* const* d_in, const int* in_sizes, int n_in,
                              void* d_out, int out_size, void* d_ws, size_t ws_size,
                              hipStream_t stream) {
    const int*   input_idx = (const int*)d_in[0];
    const int*   task      = (const int*)d_in[1];
    const float* emb       = (const float*)d_in[2];
    const float* w_ih0     = (const float*)d_in[3];
    // d_in[4] = w_hh_0: dead (h == 0)
    const float* b_ih0     = (const float*)d_in[5];
    const float* b_hh0     = (const float*)d_in[6];
    const float* w_ih1     = (const float*)d_in[7];
    // d_in[8] = w_hh_1: dead
    const float* b_ih1     = (const float*)d_in[9];
    const float* b_hh1     = (const float*)d_in[10];
    const float* w_choice  = (const float*)d_in[11];
    const float* b_choice  = (const float*)d_in[12];

    float* h0 = (float*)d_ws;
    float* h1 = h0 + HIDDEN;

    lstm_layer_kernel<<<HIDDEN, 192, 0, stream>>>(w_ih0, b_ih0, b_hh0, emb, input_idx, h0);
    lstm_layer_kernel<<<HIDDEN, 192, 0, stream>>>(w_ih1, b_ih1, b_hh1, h0, nullptr, h1);
    logits_kernel<<<CHOICE_NUM, 256, 0, stream>>>(w_choice, b_choice, h1, task, (float*)d_out);
}